// Round 2
// baseline (1074.597 us; speedup 1.0000x reference)
//
#include <hip/hip_runtime.h>
#include <stdint.h>

// 32768 samples, 4300 fp32 each. One thread per (sample,row): 20 rows/sample.
// 16 samples per block -> 320 threads (5 waves). Weights (3073 floats) staged
// in LDS; activations in registers; per-sample mixing matmuls go through LDS
// activation buffers with conflict-safe stride.

#define SPB 16           // samples per block
#define NT  (SPB * 20)   // 320 threads
#define ACT_STRIDE 164   // floats per sample slot: 164*4=656B -> bank shift 4, 16B aligned

struct P { const float* a[33]; float* out; };

// LDS weight layout (floats), row-major [dout][din] then bias[dout]
enum {
  OF_h1 = 0,     // 80+16
  OF_h2 = 96,    // 128+8
  OF_h3 = 232,   // 64+8
  OF_f1 = 304,   // 128+16
  OF_f2 = 448,   // 128+8
  OF_f3 = 584,   // 64+8
  OF_d1 = 656,   // 208+16
  OF_d2 = 880,   // 128+8
  OF_d3 = 1016,  // 64+8
  OF_g1 = 1088,  // 128+16
  OF_g2 = 1232,  // 128+8
  OF_g3 = 1368,  // 64+8
  OF_fc1 = 1440, // 928+32
  OF_fc2 = 2400, // 512+16
  OF_fc3 = 2928, // 128+8
  OF_fc4 = 3064, // 8+1
  W_TOT = 3073
};

__device__ __constant__ int WOFS[32] = {
  OF_h1, OF_h1+80,  OF_h2, OF_h2+128, OF_h3, OF_h3+64,
  OF_f1, OF_f1+128, OF_f2, OF_f2+128, OF_f3, OF_f3+64,
  OF_d1, OF_d1+208, OF_d2, OF_d2+128, OF_d3, OF_d3+64,
  OF_g1, OF_g1+128, OF_g2, OF_g2+128, OF_g3, OF_g3+64,
  OF_fc1, OF_fc1+928, OF_fc2, OF_fc2+512, OF_fc3, OF_fc3+128,
  OF_fc4, OF_fc4+8
};
__device__ __constant__ int WLEN[32] = {
  80,16, 128,8, 64,8,
  128,16, 128,8, 64,8,
  208,16, 128,8, 64,8,
  128,16, 128,8, 64,8,
  928,32, 512,16, 128,8,
  8,1
};

template<int DIN, int DOUT, bool RELU>
__device__ __forceinline__ void lin(const float* in, float* out, const float* lw) {
  const float* b = lw + DIN * DOUT;
  #pragma unroll
  for (int j = 0; j < DOUT; ++j) {
    float acc = b[j];
    #pragma unroll
    for (int k = 0; k < DIN; ++k) acc = fmaf(in[k], lw[j * DIN + k], acc);
    out[j] = RELU ? fmaxf(acc, 0.0f) : acc;
  }
}

// out8[c] = sum_n coef[n] * act[n*8+c]
__device__ __forceinline__ void mix20(const float* coef, const float* actBase, float* out8) {
  #pragma unroll
  for (int c = 0; c < 8; ++c) out8[c] = 0.0f;
  #pragma unroll
  for (int n = 0; n < 20; ++n) {
    float g = coef[n];
    const float* ar = actBase + n * 8;
    #pragma unroll
    for (int c = 0; c < 8; ++c) out8[c] = fmaf(g, ar[c], out8[c]);
  }
}

// load 20 contiguous fp32 (16B-aligned) -> registers
__device__ __forceinline__ void load20(const float* p, float* o) {
  const float4* q = (const float4*)p;
  #pragma unroll
  for (int j = 0; j < 5; ++j) {
    float4 u = q[j];
    o[j*4+0] = u.x; o[j*4+1] = u.y; o[j*4+2] = u.z; o[j*4+3] = u.w;
  }
}

__global__ __launch_bounds__(NT) void marabou_fused(P p) {
  __shared__ float w[W_TOT];
  __shared__ float actA[SPB * ACT_STRIDE];
  __shared__ float actB[SPB * ACT_STRIDE];

  const int tid = threadIdx.x;

  // Stage all weights into LDS
  #pragma unroll
  for (int a = 0; a < 32; ++a) {
    const float* src = p.a[a + 1];
    const int len = WLEN[a], ofs = WOFS[a];
    for (int i = tid; i < len; i += NT) w[ofs + i] = src[i];
  }
  __syncthreads();

  const int sl = tid / 20;
  const int r  = tid - sl * 20;
  const long gs = (long)blockIdx.x * SPB + sl;
  const float* v = p.a[0] + gs * 4300;

  float* myA = actA + sl * ACT_STRIDE;
  float* myB = actB + sl * ACT_STRIDE;

  // node_inputs row (5)
  float ni[5];
  #pragma unroll
  for (int k = 0; k < 5; ++k) ni[k] = v[r * 5 + k];

  float t16[16], t8[8], xb[8], y[8];

  // h chain: 5->16->8->8
  lin<5, 16, true>(ni, t16, w + OF_h1);
  lin<16, 8, true>(t16, t8, w + OF_h2);
  lin<8, 8, true>(t8, xb, w + OF_h3);
  #pragma unroll
  for (int c = 0; c < 8; ++c) y[c] = xb[c];

  // 8 GCN iterations
  for (int i = 0; i < 8; ++i) {
    // fblk #1
    lin<8, 16, true>(y, t16, w + OF_f1);
    lin<16, 8, true>(t16, t8, w + OF_f2);
    lin<8, 8, true>(t8, y, w + OF_f3);

    __syncthreads();                 // prior LDS readers done
    #pragma unroll
    for (int c = 0; c < 8; ++c) myA[r * 8 + c] = y[c];

    float grow[20];
    load20(v + 120 + i * 400 + r * 20, grow);
    __syncthreads();                 // writes visible

    float ym[8];
    mix20(grow, myA, ym);            // y = gcn_mats[i] @ y

    // fblk #2
    lin<8, 16, true>(ym, t16, w + OF_f1);
    lin<16, 8, true>(t16, t8, w + OF_f2);
    lin<8, 8, true>(t8, y, w + OF_f3);

    #pragma unroll
    for (int c = 0; c < 8; ++c) y[c] += xb[c];   // residual
  }

  // d chain on [ni, y] (13 -> 16 -> 8 -> 8)
  float d13[13];
  #pragma unroll
  for (int k = 0; k < 5; ++k) d13[k] = ni[k];
  #pragma unroll
  for (int k = 0; k < 8; ++k) d13[5 + k] = y[k];
  float s8[8];
  lin<13, 16, true>(d13, t16, w + OF_d1);
  lin<16, 8, true>(t16, t8, w + OF_d2);
  lin<8, 8, true>(t8, s8, w + OF_d3);

  __syncthreads();                   // prior readers (last gcn mix) done
  #pragma unroll
  for (int c = 0; c < 8; ++c) myA[r * 8 + c] = s8[c];
  float srow[20];
  load20(v + 3480 + r * 20, srow);
  __syncthreads();

  float dag[8];
  mix20(srow, myA, dag);             // dag_summary = summ_mats @ s

  // stash dag rows in B for dag_extend later
  #pragma unroll
  for (int c = 0; c < 8; ++c) myB[r * 8 + c] = dag[c];

  // g chain 8->16->8->8 (per-row)
  float g3r[8];
  lin<8, 16, true>(dag, t16, w + OF_g1);
  lin<16, 8, true>(t16, t8, w + OF_g2);
  lin<8, 8, true>(t8, g3r, w + OF_g3);

  __syncthreads();                   // dag-mix readers of A done; B writes done before this barrier
  #pragma unroll
  for (int c = 0; c < 8; ++c) myA[r * 8 + c] = g3r[c];
  __syncthreads();

  // global_summary = running @ g3   (all rows compute same result, fine)
  float runrow[20];
  load20(v + 3880, runrow);
  float glob[8];
  mix20(runrow, myA, glob);

  // dag_extend = back_map @ dag_summary
  float brow[20];
  load20(v + 3900 + r * 20, brow);
  float dext[8];
  mix20(brow, myB, dext);

  // merge (29) -> fc chain 29->32->16->8->1
  float m29[29];
  #pragma unroll
  for (int k = 0; k < 5; ++k) m29[k] = ni[k];
  #pragma unroll
  for (int k = 0; k < 8; ++k) m29[5 + k] = y[k];
  #pragma unroll
  for (int k = 0; k < 8; ++k) m29[13 + k] = dext[k];
  #pragma unroll
  for (int k = 0; k < 8; ++k) m29[21 + k] = glob[k];

  float a32[32];
  lin<29, 32, true>(m29, a32, w + OF_fc1);
  lin<32, 16, true>(a32, t16, w + OF_fc2);
  lin<16, 8, true>(t16, t8, w + OF_fc3);

  float o = w[OF_fc4 + 8];           // fc4 bias
  #pragma unroll
  for (int k = 0; k < 8; ++k) o = fmaf(t8[k], w[OF_fc4 + k], o);

  float mask = v[100 + r];
  o += mask * 10000.0f;

  p.out[gs * 20 + r] = o;
}

extern "C" void kernel_launch(void* const* d_in, const int* in_sizes, int n_in,
                              void* d_out, int out_size, void* d_ws, size_t ws_size,
                              hipStream_t stream) {
  P p;
  for (int i = 0; i < 33; ++i) p.a[i] = (const float*)d_in[i];
  p.out = (float*)d_out;

  const int B = in_sizes[0] / 4300;      // 32768
  const int nblocks = (B + SPB - 1) / SPB;
  marabou_fused<<<nblocks, NT, 0, stream>>>(p);
}